// Round 15
// baseline (137.350 us; speedup 1.0000x reference)
//
#include <hip/hip_runtime.h>
#include <math.h>

#define EPS 1e-7f

constexpr int B = 16, L = 1024, D = 256, P = 20;
constexpr int LD = L * D;     // 262144
constexpr int DD = D * D;     // 65536

typedef __attribute__((ext_vector_type(8))) _Float16 f16x8;
typedef __attribute__((ext_vector_type(4))) float f32x4;

// ---------------------------------------------------------------------------
// ws layout (float slots).  NO atomics, NO memsets.
//   tp    @0         131072    fp32 [32][B][D]  t partials
//   invU  @131072    16384     fp32 [B*L]  (only sign consumed downstream)
//   s1f   @147456    2097152   fp16 [B*L][D]
//   CT    @2244608   2097152   fp16 [B][D][L]  (s2*sqrt(invn2), transposed)
//   Gp16i @4341760   2097152   fp16 [B][D(row)][4(kc)][D(col)]  INTERLEAVED
//                              gram partials: kc-stride=256 halfs (512 B),
//                              row-stride=1024 halfs (2 KB) -> all 4 partials
//                              of a row sit in one 2 KB block (L2-local).
//   mavh  @6438912   2097152   fp16 [B*L][D]  (unscaled u; out scale-invariant)
// total 8536064 floats = 34.1 MB
// ---------------------------------------------------------------------------

__device__ inline unsigned short f2h(float x) {
    _Float16 h = (_Float16)x;
    union { _Float16 h; unsigned short u; } c; c.h = h; return c.u;
}
__device__ inline float h2f(unsigned short u) {
    union { unsigned short u; _Float16 h; } c; c.u = u; return (float)c.h;
}

// K1: one pass over s2.  Block = 32 full rows (b, m0..m0+31).  Computes
// invn2 locally, emits tp partials and transposed fp16 CT.  Grid 512.
__global__ __launch_bounds__(256) void k_prep2(const float* __restrict__ s2,
                                               float* __restrict__ tp,
                                               unsigned short* __restrict__ CT) {
    __shared__ float tile[32][257];
    __shared__ float wiv[32];   // invn2 = 1/norm
    __shared__ float wsq[32];   // sqrt(invn2)
    int tid = threadIdx.x;
    int b   = blockIdx.x >> 5, mt = blockIdx.x & 31;
    int m0  = mt * 32;
    {
        int r = tid >> 3, c0 = (tid & 7) * 32;
        const float* gp = s2 + (size_t)b * LD + (size_t)(m0 + r) * D + c0;
        float4 v[8];
#pragma unroll
        for (int q = 0; q < 8; ++q) v[q] = ((const float4*)gp)[q];
#pragma unroll
        for (int q = 0; q < 8; ++q) *(float4*)&tile[r][c0 + q * 4] = v[q];
    }
    __syncthreads();
    {
        int r = tid >> 3, seg = tid & 7;
        float s = 0.f;
#pragma unroll
        for (int k = 0; k < 32; ++k) { float v = tile[r][seg * 32 + k]; s += v * v; }
#pragma unroll
        for (int o = 4; o; o >>= 1) s += __shfl_down(s, o, 8);
        if (seg == 0) {
            float iv = 1.0f / sqrtf(fmaxf(s, EPS));
            wiv[r] = iv;
            wsq[r] = sqrtf(iv);
        }
    }
    __syncthreads();
    {
        int dc = tid;                          // d-column 0..255
        float tpart = 0.f;
        union { unsigned short us[32]; uint4 q[4]; } ph;
#pragma unroll
        for (int m = 0; m < 32; ++m) {
            float v = tile[m][dc];
            tpart += v * wiv[m];
            ph.us[m] = f2h(v * wsq[m]);
        }
        tp[(size_t)(mt * B + b) * D + dc] = tpart;
        size_t o = (size_t)b * LD + (size_t)dc * L + m0;
        *(uint4*)(CT + o)      = ph.q[0]; *(uint4*)(CT + o + 8)  = ph.q[1];
        *(uint4*)(CT + o + 16) = ph.q[2]; *(uint4*)(CT + o + 24) = ph.q[3];
    }
}

// K2: one pass over s1.  Reduces t-partials, computes invU (fp32, exact sign
// path), writes fp16 s1f.  One wave per row; grid 4096.
__global__ __launch_bounds__(256) void k_u(const float* __restrict__ s1,
                                           const float* __restrict__ tp,
                                           float* __restrict__ invU,
                                           unsigned short* __restrict__ s1f) {
    __shared__ float ts[D];
    int tid = threadIdx.x;
    {
        int b0 = (blockIdx.x * 4) >> 10;      // all 4 rows share b
        float acc = 0.f;
#pragma unroll
        for (int mc = 0; mc < 32; ++mc)
            acc += tp[(size_t)(mc * B + b0) * D + tid];
        ts[tid] = acc;
    }
    __syncthreads();

    int w = tid >> 6, lane = tid & 63;
    int row = blockIdx.x * 4 + w;             // 0..16383
    int dg = lane & 15;

    float4 sv[4];
    float up = 0.f, sq = 0.f;
#pragma unroll
    for (int j = 0; j < 4; ++j) {
        sv[j] = *(const float4*)(s1 + (size_t)row * D + dg * 4 + j * 64);
        float4 tv = *(const float4*)(ts + dg * 4 + j * 64);
        up += sv[j].x * tv.x + sv[j].y * tv.y + sv[j].z * tv.z + sv[j].w * tv.w;
        sq += sv[j].x * sv[j].x + sv[j].y * sv[j].y + sv[j].z * sv[j].z + sv[j].w * sv[j].w;
    }
#pragma unroll
    for (int o = 8; o; o >>= 1) {
        up += __shfl_down(up, o, 16);
        sq += __shfl_down(sq, o, 16);
    }
    if (lane == 0) {
        float n1v = sqrtf(fmaxf(sq, EPS));
        invU[row] = 1.0f / (up + EPS * n1v);
    }
#pragma unroll
    for (int j = 0; j < 4; ++j) {
        ushort4 h4;
        h4.x = f2h(sv[j].x); h4.y = f2h(sv[j].y);
        h4.z = f2h(sv[j].z); h4.w = f2h(sv[j].w);
        *(ushort4*)(s1f + (size_t)row * D + dg * 4 + j * 64) = h4;
    }
}

// K3: Gram via fp16 MFMA, single pass.  G = C'C, K-split x4 (256 m each).
// Writes fp16 partials INTERLEAVED: Gp16i[b][row][kc][col].
// Block: 128(i) x 64(j) tile, 4 waves 2x2 (64x32 each, 4x2 MFMA 16x16x32).
// Grid: 16 b x (2 ti x 4 tj x 4 kc) = 512 -> 2 blocks/CU.
__global__ __launch_bounds__(256) void k_gram_mfma(const unsigned short* __restrict__ CT,
                                                   unsigned short* __restrict__ Gp16i) {
    __shared__ short As[128 * 72];
    __shared__ short Bs[64 * 72];
    int tid  = threadIdx.x;
    int b    = blockIdx.x >> 5;
    int rem  = blockIdx.x & 31;
    int ti   = rem >> 4;               // 0..1
    int tj   = (rem >> 2) & 3;         // 0..3
    int kc   = rem & 3;                // 0..3
    int wave = tid >> 6, lane = tid & 63;
    int wr   = (wave >> 1) * 64, wcc = (wave & 1) * 32;
    int lr   = lane & 15, lq = lane >> 4;
    int arow = tid >> 1, ahalf = (tid & 1) * 32;   // A: 128 rows, 2 thr/row
    int brow = tid >> 2, bq = (tid & 3) * 16;      // B: 64 rows, 4 thr/row

    f32x4 acc[4][2];
#pragma unroll
    for (int i = 0; i < 4; ++i)
#pragma unroll
        for (int j = 0; j < 2; ++j) acc[i][j] = (f32x4){0.f, 0.f, 0.f, 0.f};

#pragma unroll 1
    for (int kb = 0; kb < 4; ++kb) {
        int koff = kc * 256 + kb * 64;
        __syncthreads();
        {
            const unsigned short* ga = CT + (size_t)b * LD + (size_t)(ti * 128 + arow) * L + koff + ahalf;
            uint4 a0 = ((const uint4*)ga)[0], a1 = ((const uint4*)ga)[1];
            uint4 a2 = ((const uint4*)ga)[2], a3 = ((const uint4*)ga)[3];
            const unsigned short* gb = CT + (size_t)b * LD + (size_t)(tj * 64 + brow) * L + koff + bq;
            uint4 b0 = ((const uint4*)gb)[0], b1 = ((const uint4*)gb)[1];
            short* la = &As[arow * 72 + ahalf];
            ((uint4*)la)[0] = a0; ((uint4*)la)[1] = a1;
            ((uint4*)la)[2] = a2; ((uint4*)la)[3] = a3;
            short* lb = &Bs[brow * 72 + bq];
            ((uint4*)lb)[0] = b0; ((uint4*)lb)[1] = b1;
        }
        __syncthreads();
#pragma unroll
        for (int ks = 0; ks < 2; ++ks) {
            f16x8 af[4], bfr[2];
#pragma unroll
            for (int i = 0; i < 4; ++i)
                af[i] = *(const f16x8*)&As[(wr + i * 16 + lr) * 72 + ks * 32 + lq * 8];
#pragma unroll
            for (int j = 0; j < 2; ++j)
                bfr[j] = *(const f16x8*)&Bs[(wcc + j * 16 + lr) * 72 + ks * 32 + lq * 8];
#pragma unroll
            for (int i = 0; i < 4; ++i)
#pragma unroll
                for (int j = 0; j < 2; ++j)
                    acc[i][j] = __builtin_amdgcn_mfma_f32_16x16x32_f16(af[i], bfr[j], acc[i][j], 0, 0, 0);
        }
    }
    // interleaved store: Gp16i[((b*D + row)*4 + kc)*D + col]
#pragma unroll
    for (int i = 0; i < 4; ++i)
#pragma unroll
        for (int r = 0; r < 4; ++r) {
            int row = ti * 128 + wr + i * 16 + lq * 4 + r;
            unsigned short* gr = Gp16i + ((size_t)(b * D + row) * 4 + kc) * D;
#pragma unroll
            for (int j = 0; j < 2; ++j)
                gr[tj * 64 + wcc + j * 16 + lr] = f2h(acc[i][j][r]);
        }
}

// K4: mavh = fp16(s1 @ G), with the 4 fp16 Gram partials summed INLINE in
// the B-staging.  Interleaved layout -> the 4 partial reads for a row sit in
// one 2 KB block (R12's 2 MB-stride locality bug fixed).
// Block = 64 l x 128 n, 4 waves each 64l x 32n (4x2 MFMA).  Grid 512.
__global__ __launch_bounds__(256) void k_mav_mfma(const unsigned short* __restrict__ s1f,
                                                  const unsigned short* __restrict__ Gp16i,
                                                  unsigned short* __restrict__ mavh) {
    __shared__ short As[64 * 72];
    __shared__ short Bs[128 * 72];
    int tid  = threadIdx.x;
    int b    = blockIdx.x >> 5;
    int rem  = blockIdx.x & 31;
    int lt   = rem >> 1, nt = rem & 1;
    int l0   = lt * 64, n0 = nt * 128;
    int wave = tid >> 6, lane = tid & 63;
    int wn   = wave * 32;
    int lr   = lane & 15, lq = lane >> 4;
    int arow = tid >> 2, aq = (tid & 3) * 16;      // A: 64 rows x 64 shorts
    int brow = tid >> 1, bhalf = (tid & 1) * 32;   // B: 128 rows x 64 shorts

    f32x4 acc[4][2];
#pragma unroll
    for (int i = 0; i < 4; ++i)
#pragma unroll
        for (int j = 0; j < 2; ++j) acc[i][j] = (f32x4){0.f, 0.f, 0.f, 0.f};

#pragma unroll 1
    for (int kb = 0; kb < 4; ++kb) {
        int koff = kb * 64;
        __syncthreads();
        {
            const unsigned short* ga = s1f + (size_t)(b * L + l0 + arow) * D + koff + aq;
            uint4 a0 = ((const uint4*)ga)[0], a1 = ((const uint4*)ga)[1];
            short* la = &As[arow * 72 + aq];
            ((uint4*)la)[0] = a0; ((uint4*)la)[1] = a1;
            // B: sum 4 interleaved fp16 partials (all within one 2 KB row block)
            const unsigned short* gb = Gp16i + (size_t)(b * D + n0 + brow) * 4 * D + koff + bhalf;
            short* lb = &Bs[brow * 72 + bhalf];
            union PH { uint4 q; f16x8 h; };
#pragma unroll
            for (int c = 0; c < 4; ++c) {
                PH p0, p1, p2, p3, s;
                p0.q = *(const uint4*)(gb + c * 8);
                p1.q = *(const uint4*)(gb + D + c * 8);
                p2.q = *(const uint4*)(gb + 2 * D + c * 8);
                p3.q = *(const uint4*)(gb + 3 * D + c * 8);
                s.h = (p0.h + p1.h) + (p2.h + p3.h);
                ((uint4*)lb)[c] = s.q;
            }
        }
        __syncthreads();
#pragma unroll
        for (int ks = 0; ks < 2; ++ks) {
            f16x8 af[4], bfr[2];
#pragma unroll
            for (int i = 0; i < 4; ++i)
                af[i] = *(const f16x8*)&As[(i * 16 + lr) * 72 + ks * 32 + lq * 8];
#pragma unroll
            for (int j = 0; j < 2; ++j)
                bfr[j] = *(const f16x8*)&Bs[(wn + j * 16 + lr) * 72 + ks * 32 + lq * 8];
#pragma unroll
            for (int i = 0; i < 4; ++i)
#pragma unroll
                for (int j = 0; j < 2; ++j)
                    acc[i][j] = __builtin_amdgcn_mfma_f32_16x16x32_f16(af[i], bfr[j], acc[i][j], 0, 0, 0);
        }
    }
#pragma unroll
    for (int i = 0; i < 4; ++i)
#pragma unroll
        for (int r = 0; r < 4; ++r) {
            int l = l0 + i * 16 + lq * 4 + r;
#pragma unroll
            for (int j = 0; j < 2; ++j)
                mavh[(size_t)(b * L + l) * D + n0 + wn + j * 16 + lr] = f2h(acc[i][j][r]);
        }
}

// K5: out[row,p] = sign(invU) * na * rsqrt(nb) * rsqrt(nc) over fp16 s1f/mavh.
__global__ __launch_bounds__(256) void k_out(const unsigned short* __restrict__ s1f,
                                             const unsigned short* __restrict__ mavh,
                                             const float* __restrict__ invU,
                                             const float* __restrict__ kern,
                                             float* __restrict__ out) {
    __shared__ float k2s[P * D];
    int tid = threadIdx.x;
#pragma unroll
    for (int p = 0; p < P; ++p) {
        float v = kern[p * D + tid];
        k2s[p * D + tid] = v * v;
    }
    __syncthreads();

    int w = tid >> 6, lane = tid & 63;
    int row = blockIdx.x * 4 + w;
    int dg = lane & 15, ps = lane >> 4;

    float4 sm[4], ss[4], mm[4];
#pragma unroll
    for (int j = 0; j < 4; ++j) {
        ushort4 h4 = *(const ushort4*)(s1f + (size_t)row * D + dg * 4 + j * 64);
        ushort4 m4 = *(const ushort4*)(mavh + (size_t)row * D + dg * 4 + j * 64);
        float4 sv, mv;
        sv.x = h2f(h4.x); sv.y = h2f(h4.y); sv.z = h2f(h4.z); sv.w = h2f(h4.w);
        mv.x = h2f(m4.x); mv.y = h2f(m4.y); mv.z = h2f(m4.z); mv.w = h2f(m4.w);
        sm[j].x = sv.x * mv.x; sm[j].y = sv.y * mv.y; sm[j].z = sv.z * mv.z; sm[j].w = sv.w * mv.w;
        ss[j].x = sv.x * sv.x; ss[j].y = sv.y * sv.y; ss[j].z = sv.z * sv.z; ss[j].w = sv.w * sv.w;
        mm[j].x = mv.x * mv.x; mm[j].y = mv.y * mv.y; mm[j].z = mv.z * mv.z; mm[j].w = mv.w * mv.w;
    }
    float sgn = (invU[row] < 0.f) ? -1.f : 1.f;
#pragma unroll
    for (int tI = 0; tI < 5; ++tI) {
        int p = ps + tI * 4;
        float na = 0.f, nb = 0.f, nc = 0.f;
#pragma unroll
        for (int j = 0; j < 4; ++j) {
            float4 kv = *(const float4*)&k2s[p * D + j * 64 + dg * 4];
            na += sm[j].x * kv.x + sm[j].y * kv.y + sm[j].z * kv.z + sm[j].w * kv.w;
            nb += ss[j].x * kv.x + ss[j].y * kv.y + ss[j].z * kv.z + ss[j].w * kv.w;
            nc += mm[j].x * kv.x + mm[j].y * kv.y + mm[j].z * kv.z + mm[j].w * kv.w;
        }
#pragma unroll
        for (int o = 8; o; o >>= 1) {
            na += __shfl_down(na, o, 16);
            nb += __shfl_down(nb, o, 16);
            nc += __shfl_down(nc, o, 16);
        }
        if (dg == 0) {
            out[(size_t)row * P + p] = sgn * na * rsqrtf(fmaxf(nb, EPS)) *
                                       rsqrtf(fmaxf(nc, EPS));
        }
    }
}

extern "C" void kernel_launch(void* const* d_in, const int* in_sizes, int n_in,
                              void* d_out, int out_size, void* d_ws, size_t ws_size,
                              hipStream_t stream) {
    const float* s1   = (const float*)d_in[0];
    const float* s2   = (const float*)d_in[1];
    const float* kern = (const float*)d_in[2];
    float* out = (float*)d_out;
    float* ws  = (float*)d_ws;

    float* tp   = ws;
    float* invU = ws + 131072;
    unsigned short* s1f   = (unsigned short*)(ws + 147456);
    unsigned short* CT    = (unsigned short*)(ws + 2244608);
    unsigned short* Gp16i = (unsigned short*)(ws + 4341760);
    unsigned short* mavh  = (unsigned short*)(ws + 6438912);

    k_prep2<<<512, 256, 0, stream>>>(s2, tp, CT);
    k_u<<<4096, 256, 0, stream>>>(s1, tp, invU, s1f);
    k_gram_mfma<<<512, 256, 0, stream>>>(CT, Gp16i);
    k_mav_mfma<<<512, 256, 0, stream>>>(s1f, Gp16i, mavh);
    k_out<<<4096, 256, 0, stream>>>(s1f, mavh, invU, kern, out);
}

// Round 16
// 128.826 us; speedup vs baseline: 1.0662x; 1.0662x over previous
//
#include <hip/hip_runtime.h>
#include <math.h>

#define EPS 1e-7f

constexpr int B = 16, L = 1024, D = 256, P = 20;
constexpr int LD = L * D;     // 262144
constexpr int DD = D * D;     // 65536

typedef __attribute__((ext_vector_type(8))) _Float16 f16x8;
typedef __attribute__((ext_vector_type(4))) float f32x4;

// ---------------------------------------------------------------------------
// R10 configuration — measured best (128.6 us).  NO atomics, NO memsets.
// ws layout (float slots):
//   tp    @0         131072    fp32 [32][B][D]  t partials
//   invU  @131072    16384     fp32 [B*L]  (only sign consumed downstream)
//   s1f   @147456    2097152   fp16 [B*L][D]
//   CT    @2244608   2097152   fp16 [B][D][L]  (s2*sqrt(invn2), transposed)
//   Gf    @4341760   524288    fp16 [B][D][D]
//   Gp    @4866048   4194304   fp32 [4][B][D][D]  gram K-split partials
//   mavh  @9060352   2097152   fp16 [B*L][D]  (unscaled u; out scale-invariant)
// total 11157504 floats = 44.6 MB
//
// Session rules learned (R1-R14):
//  - fp32 global atomics to small dense regions serialize (~50ns/op/line): never.
//  - separate clean-BW reduce kernel beats inline strided reduce in GEMM staging
//    (R12 +8.4us, R14 +8.8us).
//  - mav+out fusion loses to split kernels (R4 structural, R13 +4.6us).
//  - cooperative mega-kernel fails to launch under this harness (R11).
//  - fp16 single-pass GEMM == bf16x2 3-pass accuracy here (absmax 3.9e-3 both).
// ---------------------------------------------------------------------------

__device__ inline unsigned short f2h(float x) {
    _Float16 h = (_Float16)x;
    union { _Float16 h; unsigned short u; } c; c.h = h; return c.u;
}
__device__ inline float h2f(unsigned short u) {
    union { unsigned short u; _Float16 h; } c; c.u = u; return (float)c.h;
}

// K1: one pass over s2.  Block = 32 full rows (b, m0..m0+31).  Computes
// invn2 locally, emits tp partials and transposed fp16 CT.  Grid 512.
__global__ __launch_bounds__(256) void k_prep2(const float* __restrict__ s2,
                                               float* __restrict__ tp,
                                               unsigned short* __restrict__ CT) {
    __shared__ float tile[32][257];
    __shared__ float wiv[32];   // invn2 = 1/norm
    __shared__ float wsq[32];   // sqrt(invn2)
    int tid = threadIdx.x;
    int b   = blockIdx.x >> 5, mt = blockIdx.x & 31;
    int m0  = mt * 32;
    {
        int r = tid >> 3, c0 = (tid & 7) * 32;
        const float* gp = s2 + (size_t)b * LD + (size_t)(m0 + r) * D + c0;
        float4 v[8];
#pragma unroll
        for (int q = 0; q < 8; ++q) v[q] = ((const float4*)gp)[q];
#pragma unroll
        for (int q = 0; q < 8; ++q) *(float4*)&tile[r][c0 + q * 4] = v[q];
    }
    __syncthreads();
    {
        int r = tid >> 3, seg = tid & 7;
        float s = 0.f;
#pragma unroll
        for (int k = 0; k < 32; ++k) { float v = tile[r][seg * 32 + k]; s += v * v; }
#pragma unroll
        for (int o = 4; o; o >>= 1) s += __shfl_down(s, o, 8);
        if (seg == 0) {
            float iv = 1.0f / sqrtf(fmaxf(s, EPS));
            wiv[r] = iv;
            wsq[r] = sqrtf(iv);
        }
    }
    __syncthreads();
    {
        int dc = tid;                          // d-column 0..255
        float tpart = 0.f;
        union { unsigned short us[32]; uint4 q[4]; } ph;
#pragma unroll
        for (int m = 0; m < 32; ++m) {
            float v = tile[m][dc];
            tpart += v * wiv[m];
            ph.us[m] = f2h(v * wsq[m]);
        }
        tp[(size_t)(mt * B + b) * D + dc] = tpart;
        size_t o = (size_t)b * LD + (size_t)dc * L + m0;
        *(uint4*)(CT + o)      = ph.q[0]; *(uint4*)(CT + o + 8)  = ph.q[1];
        *(uint4*)(CT + o + 16) = ph.q[2]; *(uint4*)(CT + o + 24) = ph.q[3];
    }
}

// K2: one pass over s1.  Reduces t-partials, computes invU (fp32, exact sign
// path), writes fp16 s1f.  One wave per row; grid 4096.
__global__ __launch_bounds__(256) void k_u(const float* __restrict__ s1,
                                           const float* __restrict__ tp,
                                           float* __restrict__ invU,
                                           unsigned short* __restrict__ s1f) {
    __shared__ float ts[D];
    int tid = threadIdx.x;
    {
        int b0 = (blockIdx.x * 4) >> 10;      // all 4 rows share b
        float acc = 0.f;
#pragma unroll
        for (int mc = 0; mc < 32; ++mc)
            acc += tp[(size_t)(mc * B + b0) * D + tid];
        ts[tid] = acc;
    }
    __syncthreads();

    int w = tid >> 6, lane = tid & 63;
    int row = blockIdx.x * 4 + w;             // 0..16383
    int dg = lane & 15;

    float4 sv[4];
    float up = 0.f, sq = 0.f;
#pragma unroll
    for (int j = 0; j < 4; ++j) {
        sv[j] = *(const float4*)(s1 + (size_t)row * D + dg * 4 + j * 64);
        float4 tv = *(const float4*)(ts + dg * 4 + j * 64);
        up += sv[j].x * tv.x + sv[j].y * tv.y + sv[j].z * tv.z + sv[j].w * tv.w;
        sq += sv[j].x * sv[j].x + sv[j].y * sv[j].y + sv[j].z * sv[j].z + sv[j].w * sv[j].w;
    }
#pragma unroll
    for (int o = 8; o; o >>= 1) {
        up += __shfl_down(up, o, 16);
        sq += __shfl_down(sq, o, 16);
    }
    if (lane == 0) {
        float n1v = sqrtf(fmaxf(sq, EPS));
        invU[row] = 1.0f / (up + EPS * n1v);
    }
#pragma unroll
    for (int j = 0; j < 4; ++j) {
        ushort4 h4;
        h4.x = f2h(sv[j].x); h4.y = f2h(sv[j].y);
        h4.z = f2h(sv[j].z); h4.w = f2h(sv[j].w);
        *(ushort4*)(s1f + (size_t)row * D + dg * 4 + j * 64) = h4;
    }
}

// K3: Gram via fp16 MFMA, single pass.  G = C'C, K-split x4 (256 m each).
// Block: 128(i) x 64(j) tile, 4 waves 2x2 (64x32 each, 4x2 MFMA 16x16x32).
// Grid: 16 b x (2 ti x 4 tj x 4 kc) = 512 -> 2 blocks/CU.
__global__ __launch_bounds__(256) void k_gram_mfma(const unsigned short* __restrict__ CT,
                                                   float* __restrict__ Gp) {
    __shared__ short As[128 * 72];
    __shared__ short Bs[64 * 72];
    int tid  = threadIdx.x;
    int b    = blockIdx.x >> 5;
    int rem  = blockIdx.x & 31;
    int ti   = rem >> 4;               // 0..1
    int tj   = (rem >> 2) & 3;         // 0..3
    int kc   = rem & 3;                // 0..3
    int wave = tid >> 6, lane = tid & 63;
    int wr   = (wave >> 1) * 64, wcc = (wave & 1) * 32;
    int lr   = lane & 15, lq = lane >> 4;
    int arow = tid >> 1, ahalf = (tid & 1) * 32;   // A: 128 rows, 2 thr/row
    int brow = tid >> 2, bq = (tid & 3) * 16;      // B: 64 rows, 4 thr/row

    f32x4 acc[4][2];
#pragma unroll
    for (int i = 0; i < 4; ++i)
#pragma unroll
        for (int j = 0; j < 2; ++j) acc[i][j] = (f32x4){0.f, 0.f, 0.f, 0.f};

#pragma unroll 1
    for (int kb = 0; kb < 4; ++kb) {
        int koff = kc * 256 + kb * 64;
        __syncthreads();
        {
            const unsigned short* ga = CT + (size_t)b * LD + (size_t)(ti * 128 + arow) * L + koff + ahalf;
            uint4 a0 = ((const uint4*)ga)[0], a1 = ((const uint4*)ga)[1];
            uint4 a2 = ((const uint4*)ga)[2], a3 = ((const uint4*)ga)[3];
            const unsigned short* gb = CT + (size_t)b * LD + (size_t)(tj * 64 + brow) * L + koff + bq;
            uint4 b0 = ((const uint4*)gb)[0], b1 = ((const uint4*)gb)[1];
            short* la = &As[arow * 72 + ahalf];
            ((uint4*)la)[0] = a0; ((uint4*)la)[1] = a1;
            ((uint4*)la)[2] = a2; ((uint4*)la)[3] = a3;
            short* lb = &Bs[brow * 72 + bq];
            ((uint4*)lb)[0] = b0; ((uint4*)lb)[1] = b1;
        }
        __syncthreads();
#pragma unroll
        for (int ks = 0; ks < 2; ++ks) {
            f16x8 af[4], bfr[2];
#pragma unroll
            for (int i = 0; i < 4; ++i)
                af[i] = *(const f16x8*)&As[(wr + i * 16 + lr) * 72 + ks * 32 + lq * 8];
#pragma unroll
            for (int j = 0; j < 2; ++j)
                bfr[j] = *(const f16x8*)&Bs[(wcc + j * 16 + lr) * 72 + ks * 32 + lq * 8];
#pragma unroll
            for (int i = 0; i < 4; ++i)
#pragma unroll
                for (int j = 0; j < 2; ++j)
                    acc[i][j] = __builtin_amdgcn_mfma_f32_16x16x32_f16(af[i], bfr[j], acc[i][j], 0, 0, 0);
        }
    }
    float* gout = Gp + ((size_t)(kc * B + b)) * DD;
#pragma unroll
    for (int i = 0; i < 4; ++i)
#pragma unroll
        for (int r = 0; r < 4; ++r) {
            int row = ti * 128 + wr + i * 16 + lq * 4 + r;
#pragma unroll
            for (int j = 0; j < 2; ++j)
                gout[(size_t)row * D + tj * 64 + wcc + j * 16 + lr] = acc[i][j][r];
        }
}

// K4: reduce 4 gram partials; emit fp16 Gf.  (Separate clean-BW kernel —
// R12/R14 showed inline reduce in mav staging costs ~2x more.)
__global__ __launch_bounds__(256) void k_reduceG(const float* __restrict__ Gp,
                                                 unsigned short* __restrict__ Gf) {
    size_t i = ((size_t)blockIdx.x * 256 + threadIdx.x) * 4;
    float4 s = *(const float4*)(Gp + i);
#pragma unroll
    for (int kc = 1; kc < 4; ++kc) {
        float4 a = *(const float4*)(Gp + (size_t)kc * B * DD + i);
        s.x += a.x; s.y += a.y; s.z += a.z; s.w += a.w;
    }
    ushort4 h4;
    h4.x = f2h(s.x); h4.y = f2h(s.y); h4.z = f2h(s.z); h4.w = f2h(s.w);
    *(ushort4*)(Gf + i) = h4;
}

// K5: mavh = fp16(s1 @ G)  (UNSCALED — invU sign applied in k_out; out is
// scale-invariant in mav so the magnitude of invU never matters).
// Block = 64 l x 128 n, 4 waves each 64l x 32n (4x2 MFMA).  Grid 512.
__global__ __launch_bounds__(256) void k_mav_mfma(const unsigned short* __restrict__ s1f,
                                                  const unsigned short* __restrict__ Gf,
                                                  unsigned short* __restrict__ mavh) {
    __shared__ short As[64 * 72];
    __shared__ short Bs[128 * 72];
    int tid  = threadIdx.x;
    int b    = blockIdx.x >> 5;
    int rem  = blockIdx.x & 31;
    int lt   = rem >> 1, nt = rem & 1;
    int l0   = lt * 64, n0 = nt * 128;
    int wave = tid >> 6, lane = tid & 63;
    int wn   = wave * 32;
    int lr   = lane & 15, lq = lane >> 4;
    int arow = tid >> 2, aq = (tid & 3) * 16;      // A: 64 rows x 64 shorts
    int brow = tid >> 1, bhalf = (tid & 1) * 32;   // B: 128 rows x 64 shorts

    f32x4 acc[4][2];
#pragma unroll
    for (int i = 0; i < 4; ++i)
#pragma unroll
        for (int j = 0; j < 2; ++j) acc[i][j] = (f32x4){0.f, 0.f, 0.f, 0.f};

#pragma unroll 1
    for (int kb = 0; kb < 4; ++kb) {
        int koff = kb * 64;
        __syncthreads();
        {
            const unsigned short* ga = s1f + (size_t)(b * L + l0 + arow) * D + koff + aq;
            uint4 a0 = ((const uint4*)ga)[0], a1 = ((const uint4*)ga)[1];
            const unsigned short* gb = Gf + (size_t)b * DD + (size_t)(n0 + brow) * D + koff + bhalf;
            uint4 b0 = ((const uint4*)gb)[0], b1 = ((const uint4*)gb)[1];
            uint4 b2 = ((const uint4*)gb)[2], b3 = ((const uint4*)gb)[3];
            short* la = &As[arow * 72 + aq];
            ((uint4*)la)[0] = a0; ((uint4*)la)[1] = a1;
            short* lb = &Bs[brow * 72 + bhalf];
            ((uint4*)lb)[0] = b0; ((uint4*)lb)[1] = b1;
            ((uint4*)lb)[2] = b2; ((uint4*)lb)[3] = b3;
        }
        __syncthreads();
#pragma unroll
        for (int ks = 0; ks < 2; ++ks) {
            f16x8 af[4], bfr[2];
#pragma unroll
            for (int i = 0; i < 4; ++i)
                af[i] = *(const f16x8*)&As[(i * 16 + lr) * 72 + ks * 32 + lq * 8];
#pragma unroll
            for (int j = 0; j < 2; ++j)
                bfr[j] = *(const f16x8*)&Bs[(wn + j * 16 + lr) * 72 + ks * 32 + lq * 8];
#pragma unroll
            for (int i = 0; i < 4; ++i)
#pragma unroll
                for (int j = 0; j < 2; ++j)
                    acc[i][j] = __builtin_amdgcn_mfma_f32_16x16x32_f16(af[i], bfr[j], acc[i][j], 0, 0, 0);
        }
    }
#pragma unroll
    for (int i = 0; i < 4; ++i)
#pragma unroll
        for (int r = 0; r < 4; ++r) {
            int l = l0 + i * 16 + lq * 4 + r;
#pragma unroll
            for (int j = 0; j < 2; ++j)
                mavh[(size_t)(b * L + l) * D + n0 + wn + j * 16 + lr] = f2h(acc[i][j][r]);
        }
}

// K6: out[row,p] = sign(invU) * na * rsqrt(nb) * rsqrt(nc) over fp16 s1f/mavh.
__global__ __launch_bounds__(256) void k_out(const unsigned short* __restrict__ s1f,
                                             const unsigned short* __restrict__ mavh,
                                             const float* __restrict__ invU,
                                             const float* __restrict__ kern,
                                             float* __restrict__ out) {
    __shared__ float k2s[P * D];
    int tid = threadIdx.x;
#pragma unroll
    for (int p = 0; p < P; ++p) {
        float v = kern[p * D + tid];
        k2s[p * D + tid] = v * v;
    }
    __syncthreads();

    int w = tid >> 6, lane = tid & 63;
    int row = blockIdx.x * 4 + w;
    int dg = lane & 15, ps = lane >> 4;

    float4 sm[4], ss[4], mm[4];
#pragma unroll
    for (int j = 0; j < 4; ++j) {
        ushort4 h4 = *(const ushort4*)(s1f + (size_t)row * D + dg * 4 + j * 64);
        ushort4 m4 = *(const ushort4*)(mavh + (size_t)row * D + dg * 4 + j * 64);
        float4 sv, mv;
        sv.x = h2f(h4.x); sv.y = h2f(h4.y); sv.z = h2f(h4.z); sv.w = h2f(h4.w);
        mv.x = h2f(m4.x); mv.y = h2f(m4.y); mv.z = h2f(m4.z); mv.w = h2f(m4.w);
        sm[j].x = sv.x * mv.x; sm[j].y = sv.y * mv.y; sm[j].z = sv.z * mv.z; sm[j].w = sv.w * mv.w;
        ss[j].x = sv.x * sv.x; ss[j].y = sv.y * sv.y; ss[j].z = sv.z * sv.z; ss[j].w = sv.w * sv.w;
        mm[j].x = mv.x * mv.x; mm[j].y = mv.y * mv.y; mm[j].z = mv.z * mv.z; mm[j].w = mv.w * mv.w;
    }
    float sgn = (invU[row] < 0.f) ? -1.f : 1.f;
#pragma unroll
    for (int tI = 0; tI < 5; ++tI) {
        int p = ps + tI * 4;
        float na = 0.f, nb = 0.f, nc = 0.f;
#pragma unroll
        for (int j = 0; j < 4; ++j) {
            float4 kv = *(const float4*)&k2s[p * D + j * 64 + dg * 4];
            na += sm[j].x * kv.x + sm[j].y * kv.y + sm[j].z * kv.z + sm[j].w * kv.w;
            nb += ss[j].x * kv.x + ss[j].y * kv.y + ss[j].z * kv.z + ss[j].w * kv.w;
            nc += mm[j].x * kv.x + mm[j].y * kv.y + mm[j].z * kv.z + mm[j].w * kv.w;
        }
#pragma unroll
        for (int o = 8; o; o >>= 1) {
            na += __shfl_down(na, o, 16);
            nb += __shfl_down(nb, o, 16);
            nc += __shfl_down(nc, o, 16);
        }
        if (dg == 0) {
            out[(size_t)row * P + p] = sgn * na * rsqrtf(fmaxf(nb, EPS)) *
                                       rsqrtf(fmaxf(nc, EPS));
        }
    }
}

extern "C" void kernel_launch(void* const* d_in, const int* in_sizes, int n_in,
                              void* d_out, int out_size, void* d_ws, size_t ws_size,
                              hipStream_t stream) {
    const float* s1   = (const float*)d_in[0];
    const float* s2   = (const float*)d_in[1];
    const float* kern = (const float*)d_in[2];
    float* out = (float*)d_out;
    float* ws  = (float*)d_ws;

    float* tp   = ws;
    float* invU = ws + 131072;
    unsigned short* s1f  = (unsigned short*)(ws + 147456);
    unsigned short* CT   = (unsigned short*)(ws + 2244608);
    unsigned short* Gf   = (unsigned short*)(ws + 4341760);
    float* Gp   = ws + 4866048;
    unsigned short* mavh = (unsigned short*)(ws + 9060352);

    k_prep2<<<512, 256, 0, stream>>>(s2, tp, CT);
    k_u<<<4096, 256, 0, stream>>>(s1, tp, invU, s1f);
    k_gram_mfma<<<512, 256, 0, stream>>>(CT, Gp);
    k_reduceG<<<1024, 256, 0, stream>>>(Gp, Gf);
    k_mav_mfma<<<512, 256, 0, stream>>>(s1f, Gf, mavh);
    k_out<<<4096, 256, 0, stream>>>(s1f, mavh, invU, kern, out);
}